// Round 2
// 405.483 us; speedup vs baseline: 1.0222x; 1.0222x over previous
//
#include <hip/hip_runtime.h>

// Overlaps: out[i,j] = IoU(boxes0[i], boxes1[j]) if (label,batch) match else 0
// 1e8 fp32 outputs = 400 MB -> write floor ~65 us @ 6.1 TB/s (fill-demonstrated).
// R2-proven structure: 8 rows x 4 cols per thread. NO __launch_bounds__ min-waves
// (VGPR cap caused spills in R4/R5).
//
// R7 (= R6 with compile fix):
//  - Sparsity early-out: keys have 80*8=640 distinct values -> P(match)=1/640.
//    Per wave-row, P(any of 256 outputs matches) ~= 33%, so 67% of wave-row
//    iterations skip the whole IoU float pipeline via a wave-uniform __any()
//    vote on the int key compares, storing zeros directly.
//  - Nontemporal stores: output is streaming, never re-read. NOTE:
//    __builtin_nontemporal_store requires a clang ext_vector_type, not HIP's
//    float4 class -> use fx4 typedef.

typedef float fx4 __attribute__((ext_vector_type(4)));

constexpr int ROWS_PER_BLOCK = 8;
constexpr int COLS_PER_BLOCK = 1024;  // 256 threads * 4 cols

__global__ __launch_bounds__(256) void overlaps_kernel(
    const float4* __restrict__ boxes0,   // [n0] xyxy
    const int*    __restrict__ labels0,  // [n0]
    const int*    __restrict__ batches0, // [n0]
    const float4* __restrict__ boxes1,   // [n1] xyxy
    const int*    __restrict__ labels1,  // [n1]
    const int*    __restrict__ batches1, // [n1]
    float*        __restrict__ out,      // [n0, n1]
    int n0, int n1)
{
    const int j4 = blockIdx.x * COLS_PER_BLOCK + threadIdx.x * 4;
    if (j4 >= n1) return;

    const int r0   = blockIdx.y * ROWS_PER_BLOCK;
    const int rend = (r0 + ROWS_PER_BLOCK < n0) ? (r0 + ROWS_PER_BLOCK) : n0;

    if (j4 + 3 < n1) {
        // ---- column prologue: loaded once, reused for all rows ----
        const int4 l1v = *reinterpret_cast<const int4*>(labels1 + j4);
        const int4 t1v = *reinterpret_cast<const int4*>(batches1 + j4);
        int k1[4];
        k1[0] = (t1v.x << 16) | (l1v.x & 0xFFFF);
        k1[1] = (t1v.y << 16) | (l1v.y & 0xFFFF);
        k1[2] = (t1v.z << 16) | (l1v.z & 0xFFFF);
        k1[3] = (t1v.w << 16) | (l1v.w & 0xFFFF);

        float4 b1[4];
        float  area1[4];
        #pragma unroll
        for (int k = 0; k < 4; ++k) {
            b1[k] = boxes1[j4 + k];
            area1[k] = (b1[k].z - b1[k].x) * (b1[k].w - b1[k].y);
        }

        float* orow = out + (size_t)r0 * n1 + j4;

        #pragma unroll 4
        for (int r = r0; r < rend; ++r) {
            // block-uniform -> scalar loads
            const int k0 = (batches0[r] << 16) | (labels0[r] & 0xFFFF);

            bool m[4];
            #pragma unroll
            for (int k = 0; k < 4; ++k) m[k] = (k1[k] == k0);

            fx4 res = (fx4)(0.0f);

            // wave-uniform vote: 67% of wave-rows have zero matches across all
            // 64 lanes x 4 cols -> skip the entire IoU float pipeline.
            if (__any(m[0] || m[1] || m[2] || m[3])) {
                const float4 b0    = boxes0[r];
                const float  area0 = (b0.z - b0.x) * (b0.w - b0.y);
                #pragma unroll
                for (int k = 0; k < 4; ++k) {
                    const float x1 = fmaxf(b0.x, b1[k].x);
                    const float y1 = fmaxf(b0.y, b1[k].y);
                    const float x2 = fminf(b0.z, b1[k].z);
                    const float y2 = fminf(b0.w, b1[k].w);
                    const float inter = fmaxf(x2 - x1, 0.0f) * fmaxf(y2 - y1, 0.0f);
                    const float uni = (area0 + area1[k]) - inter;
                    float v = inter * __builtin_amdgcn_rcpf(uni);
                    v = (uni > 0.0f) ? v : 0.0f;
                    res[k] = m[k] ? v : 0.0f;
                }
            }

            __builtin_nontemporal_store(res, reinterpret_cast<fx4*>(orow));
            orow += n1;
        }
    } else {
        // scalar tail (n1 not a multiple of 4)
        for (int r = r0; r < rend; ++r) {
            const float4 b0 = boxes0[r];
            const int    k0 = (batches0[r] << 16) | (labels0[r] & 0xFFFF);
            const float  area0 = (b0.z - b0.x) * (b0.w - b0.y);
            for (int j = j4; j < n1; ++j) {
                float v = 0.0f;
                const int kj = (batches1[j] << 16) | (labels1[j] & 0xFFFF);
                if (kj == k0) {
                    const float4 bb = boxes1[j];
                    const float x1 = fmaxf(b0.x, bb.x);
                    const float y1 = fmaxf(b0.y, bb.y);
                    const float x2 = fminf(b0.z, bb.z);
                    const float y2 = fminf(b0.w, bb.w);
                    const float inter = fmaxf(x2 - x1, 0.0f) * fmaxf(y2 - y1, 0.0f);
                    const float a1 = (bb.z - bb.x) * (bb.w - bb.y);
                    const float uni = area0 + a1 - inter;
                    v = (uni > 0.0f) ? (inter / uni) : 0.0f;
                }
                out[(size_t)r * n1 + j] = v;
            }
        }
    }
}

extern "C" void kernel_launch(void* const* d_in, const int* in_sizes, int n_in,
                              void* d_out, int out_size, void* d_ws, size_t ws_size,
                              hipStream_t stream) {
    const float4* boxes0   = (const float4*)d_in[0];
    const int*    labels0  = (const int*)   d_in[1];
    const int*    batches0 = (const int*)   d_in[2];
    const float4* boxes1   = (const float4*)d_in[3];
    const int*    labels1  = (const int*)   d_in[4];
    const int*    batches1 = (const int*)   d_in[5];
    float*        out      = (float*)d_out;

    const int n0 = in_sizes[1];
    const int n1 = in_sizes[4];

    const int gx = (n1 + COLS_PER_BLOCK - 1) / COLS_PER_BLOCK;
    const int gy = (n0 + ROWS_PER_BLOCK - 1) / ROWS_PER_BLOCK;
    dim3 grid(gx, gy);

    overlaps_kernel<<<grid, 256, 0, stream>>>(
        boxes0, labels0, batches0, boxes1, labels1, batches1, out, n0, n1);
}